// Round 2
// baseline (244.473 us; speedup 1.0000x reference)
//
#include <hip/hip_runtime.h>

#define B_ 4
#define S_ 4096
#define H_ 16
#define D_ 1024
#define HD_ 64

// (tanh(x)+1)/2 == sigmoid(2x)
__device__ __forceinline__ float featmap(float x) {
  float e = __expf(-2.0f * x);
  return __builtin_amdgcn_rcpf(1.0f + e);
}

// ---------------- Phase 1: partial KV (64x64) + partial ksum per (b,h,chunk)
__global__ __launch_bounds__(256, 2) void mh_p1(
    const float* __restrict__ kg, const float* __restrict__ vg,
    float* __restrict__ kvp, float* __restrict__ kredp, int nc) {
  __shared__ float kt[64][64];
  __shared__ float vt[64][64];
  __shared__ float ksr[4][64];

  const int bid = blockIdx.x;       // 0..64*nc-1
  const int bh  = bid & 63;         // b*16+h
  const int c   = bid >> 6;         // chunk
  const int b   = bh >> 4, h = bh & 15;
  const int t    = threadIdx.x;
  const int w    = t >> 6;          // wave 0..3
  const int lane = t & 63;
  const int dg = lane >> 3, eg = lane & 7;
  const int d0 = dg * 8, e0 = eg * 8;

  const size_t rowbase = (size_t)b * S_ * D_ + (size_t)h * HD_;
  const float* kb = kg + rowbase;
  const float* vb = vg + rowbase;
  const int ch = S_ / nc;
  const int s0 = c * ch;
  const int ntiles = ch / 64;

  float acc[8][8];
#pragma unroll
  for (int i = 0; i < 8; ++i)
#pragma unroll
    for (int j = 0; j < 8; ++j) acc[i][j] = 0.f;
  float ks = 0.f;  // partial column-sum of sigmoid(k), column = lane

#pragma unroll 1
  for (int tile = 0; tile < ntiles; ++tile) {
    const int rb = s0 + tile * 64 + w * 16;
    // wave w owns rows [w*16, w*16+16) -> no cross-wave hazard, no barrier
#pragma unroll
    for (int i = 0; i < 16; ++i) {
      const size_t g = (size_t)(rb + i) * D_ + lane;
      float kh = featmap(kb[g]);
      float vv = vb[g];
      kt[w * 16 + i][lane] = kh;
      vt[w * 16 + i][lane] = vv;
      ks += kh;
    }
#pragma unroll
    for (int i = 0; i < 16; ++i) {
      const int r = w * 16 + i;
      float4 k0 = *(const float4*)&kt[r][d0];
      float4 k1 = *(const float4*)&kt[r][d0 + 4];
      float4 v0 = *(const float4*)&vt[r][e0];
      float4 v1 = *(const float4*)&vt[r][e0 + 4];
      float kd[8] = {k0.x, k0.y, k0.z, k0.w, k1.x, k1.y, k1.z, k1.w};
      float ve[8] = {v0.x, v0.y, v0.z, v0.w, v1.x, v1.y, v1.z, v1.w};
#pragma unroll
      for (int di = 0; di < 8; ++di)
#pragma unroll
        for (int ej = 0; ej < 8; ++ej) acc[di][ej] += kd[di] * ve[ej];
    }
  }

  // ---- reduce 4 wave replicas (tree through LDS), no atomics
  ksr[w][lane] = ks;
  __syncthreads();
  float* ktf = &kt[0][0];
  float* vtf = &vt[0][0];
  if (w >= 2) {
    float* dst = (w == 2) ? ktf : vtf;
#pragma unroll
    for (int di = 0; di < 8; ++di) {
      float4 a = {acc[di][0], acc[di][1], acc[di][2], acc[di][3]};
      float4 bq = {acc[di][4], acc[di][5], acc[di][6], acc[di][7]};
      *(float4*)&dst[(d0 + di) * 64 + e0] = a;
      *(float4*)&dst[(d0 + di) * 64 + e0 + 4] = bq;
    }
  }
  __syncthreads();
  if (w < 2) {
    const float* src = (w == 0) ? ktf : vtf;
#pragma unroll
    for (int di = 0; di < 8; ++di)
#pragma unroll
      for (int ej = 0; ej < 8; ++ej) acc[di][ej] += src[(d0 + di) * 64 + e0 + ej];
  }
  __syncthreads();
  if (w == 1) {
#pragma unroll
    for (int di = 0; di < 8; ++di) {
      float4 a = {acc[di][0], acc[di][1], acc[di][2], acc[di][3]};
      float4 bq = {acc[di][4], acc[di][5], acc[di][6], acc[di][7]};
      *(float4*)&ktf[(d0 + di) * 64 + e0] = a;
      *(float4*)&ktf[(d0 + di) * 64 + e0 + 4] = bq;
    }
  }
  __syncthreads();
  if (w == 0) {
    float* dst = kvp + ((size_t)(c * 64 + bh)) * 4096;
#pragma unroll
    for (int di = 0; di < 8; ++di) {
#pragma unroll
      for (int ej = 0; ej < 8; ++ej) acc[di][ej] += ktf[(d0 + di) * 64 + e0 + ej];
      float4 a = {acc[di][0], acc[di][1], acc[di][2], acc[di][3]};
      float4 bq = {acc[di][4], acc[di][5], acc[di][6], acc[di][7]};
      *(float4*)&dst[(d0 + di) * 64 + e0] = a;
      *(float4*)&dst[(d0 + di) * 64 + e0 + 4] = bq;
    }
  }
  if (t < 64) {
    float tot = ksr[0][t] + ksr[1][t] + ksr[2][t] + ksr[3][t];
    kredp[(size_t)(c * 64 + bh) * 64 + t] = tot;
  }
}

// ---------------- Phase 1.5: reduce chunk partials -> kv, kred
__global__ __launch_bounds__(256) void mh_p15(
    const float* __restrict__ kvp, const float* __restrict__ kredp,
    float* __restrict__ kv, float* __restrict__ kred, int nc) {
  const int i = blockIdx.x * 256 + threadIdx.x;  // 0..262143
  float s = 0.f;
#pragma unroll 1
  for (int c = 0; c < nc; ++c) s += kvp[(size_t)c * (64 * 4096) + i];
  kv[i] = s;
  if (i < 64 * 64) {
    float r = 0.f;
#pragma unroll 1
    for (int c = 0; c < nc; ++c) r += kredp[c * 4096 + i];
    kred[i] = r + 1e-8f;
  }
}

// ---------------- Phase 2: out = z * qh @ KV
// Block = one (b,h) x 128 s-rows. Waves 0,1 -> e in [0,32); waves 2,3 -> [32,64)
// (e-range is wave-uniform so kv row loads stay scalar). Lane owns one s-row,
// 32 accumulators; q row prefetched into 64 VGPRs up front (16 loads in flight).
__global__ __launch_bounds__(256, 2) void mh_p2(
    const float* __restrict__ qg, const float* __restrict__ kv,
    const float* __restrict__ kred, float* __restrict__ outg) {
  const int bid = blockIdx.x;        // 0..2047
  const int bh = bid >> 5;           // 0..63
  const int rc = bid & 31;           // 128-row chunk
  const int b = bh >> 4, h = bh & 15;
  const int t = threadIdx.x;
  const int w = t >> 6, lane = t & 63;
  const int eh = w >> 1;                      // e-half, wave-uniform
  const int rr = ((w & 1) << 6) + lane;       // 0..127
  const int s = rc * 128 + rr;
  const int e0 = eh * 32;

  const float* qrow = qg + (size_t)(b * S_ + s) * D_ + h * HD_;
  const float* kvb = kv + (size_t)bh * 4096 + e0;  // uniform
  const float* krd = kred + bh * 64;               // uniform

  // prefetch + featmap the whole q row (16 independent loads)
  float qh[64];
#pragma unroll
  for (int i = 0; i < 16; ++i) {
    float4 qv = *(const float4*)(qrow + 4 * i);
    qh[4 * i + 0] = qv.x;
    qh[4 * i + 1] = qv.y;
    qh[4 * i + 2] = qv.z;
    qh[4 * i + 3] = qv.w;
  }
#pragma unroll
  for (int i = 0; i < 64; ++i) qh[i] = featmap(qh[i]);

  float acc[32];
#pragma unroll
  for (int e = 0; e < 32; ++e) acc[e] = 0.f;
  float zacc = 0.f;

#pragma unroll 4
  for (int d = 0; d < 64; ++d) {
    const float qd = qh[d];
    zacc += qd * krd[d];
    const float* row = kvb + d * 64;  // uniform -> s_load expected
#pragma unroll
    for (int e = 0; e < 32; ++e) acc[e] += qd * row[e];
  }

  const float z = 1.0f / zacc;
  float* orow = outg + (size_t)(b * S_ + s) * D_ + h * HD_ + e0;
#pragma unroll
  for (int e4 = 0; e4 < 8; ++e4) {
    float4 o = {acc[e4 * 4] * z, acc[e4 * 4 + 1] * z,
                acc[e4 * 4 + 2] * z, acc[e4 * 4 + 3] * z};
    *(float4*)(orow + e4 * 4) = o;
  }
}

extern "C" void kernel_launch(void* const* d_in, const int* in_sizes, int n_in,
                              void* d_out, int out_size, void* d_ws, size_t ws_size,
                              hipStream_t stream) {
  const float* q = (const float*)d_in[0];
  const float* k = (const float*)d_in[1];
  const float* v = (const float*)d_in[2];
  float* out = (float*)d_out;
  float* ws = (float*)d_ws;

  // choose chunk count by available workspace (nc=16 needs ~17.3 MB)
  const int nc = (ws_size >= (size_t)18 * 1024 * 1024) ? 16 : 8;

  float* kv    = ws;                            // 262144 floats (1 MiB)
  float* kred  = ws + 262144;                   // 4096 floats
  float* kvp   = ws + 262144 + 4096;            // nc * 1 MiB
  float* kredp = kvp + (size_t)nc * 262144;     // nc * 4096 floats

  mh_p1 <<<64 * nc, 256, 0, stream>>>(k, v, kvp, kredp, nc);
  mh_p15<<<1024,    256, 0, stream>>>(kvp, kredp, kv, kred, nc);
  mh_p2 <<<64 * 32, 256, 0, stream>>>(q, kv, kred, out);
}

// Round 3
// 229.192 us; speedup vs baseline: 1.0667x; 1.0667x over previous
//
#include <hip/hip_runtime.h>

#define B_ 4
#define S_ 4096
#define H_ 16
#define D_ 1024
#define HD_ 64

// (tanh(x)+1)/2 == sigmoid(2x)
__device__ __forceinline__ float featmap(float x) {
  float e = __expf(-2.0f * x);
  return __builtin_amdgcn_rcpf(1.0f + e);
}

// ---------------- Phase 1: partial KV (64x64) + partial ksum per (b,h,chunk)
// Stage only featmap(k) in LDS (v is read directly from global: no transform
// needed, slices land in the same 256B row -> no extra HBM traffic).
__global__ __launch_bounds__(256, 4) void mh_p1(
    const float* __restrict__ kg, const float* __restrict__ vg,
    float* __restrict__ kvp, float* __restrict__ kredp, int nc) {
  __shared__ float kt[64][64];     // featmap(k) tile (own-wave rows only)
  __shared__ float red2[64][64];   // reduction scratch
  __shared__ float ksr[4][64];

  const int bid = blockIdx.x;       // 0..64*nc-1
  const int bh  = bid & 63;         // b*16+h
  const int c   = bid >> 6;         // chunk
  const int b   = bh >> 4, h = bh & 15;
  const int t    = threadIdx.x;
  const int w    = t >> 6;          // wave 0..3
  const int lane = t & 63;
  const int dg = lane >> 3, eg = lane & 7;
  const int d0 = dg * 8, e0 = eg * 8;

  const size_t rowbase = (size_t)b * S_ * D_ + (size_t)h * HD_;
  const float* kb = kg + rowbase;
  const float* vb = vg + rowbase;
  const int ch = S_ / nc;
  const int s0 = c * ch;
  const int ntiles = ch / 64;

  float acc[8][8];
#pragma unroll
  for (int i = 0; i < 8; ++i)
#pragma unroll
    for (int j = 0; j < 8; ++j) acc[i][j] = 0.f;
  float ks = 0.f;  // partial column-sum of sigmoid(k), column = lane

#pragma unroll 1
  for (int tile = 0; tile < ntiles; ++tile) {
    const int rb = s0 + tile * 64 + w * 16;
    // wave w owns rows [w*16, w*16+16): no cross-wave hazard, no barrier
#pragma unroll
    for (int i = 0; i < 16; ++i) {
      const size_t g = (size_t)(rb + i) * D_ + lane;
      float kh = featmap(kb[g]);
      kt[w * 16 + i][lane] = kh;
      ks += kh;
    }
#pragma unroll
    for (int i = 0; i < 16; ++i) {
      const int r = w * 16 + i;
      float4 k0 = *(const float4*)&kt[r][d0];
      float4 k1 = *(const float4*)&kt[r][d0 + 4];
      const float* vrow = vb + (size_t)(rb + i) * D_;
      float4 v0 = *(const float4*)(vrow + e0);
      float4 v1 = *(const float4*)(vrow + e0 + 4);
      float kd[8] = {k0.x, k0.y, k0.z, k0.w, k1.x, k1.y, k1.z, k1.w};
      float ve[8] = {v0.x, v0.y, v0.z, v0.w, v1.x, v1.y, v1.z, v1.w};
#pragma unroll
      for (int di = 0; di < 8; ++di)
#pragma unroll
        for (int ej = 0; ej < 8; ++ej) acc[di][ej] += kd[di] * ve[ej];
    }
  }

  // ---- reduce 4 wave replicas (tree through LDS), no atomics
  ksr[w][lane] = ks;
  __syncthreads();
  float* ktf = &kt[0][0];
  float* vtf = &red2[0][0];
  if (w >= 2) {
    float* dst = (w == 2) ? ktf : vtf;
#pragma unroll
    for (int di = 0; di < 8; ++di) {
      float4 a = {acc[di][0], acc[di][1], acc[di][2], acc[di][3]};
      float4 bq = {acc[di][4], acc[di][5], acc[di][6], acc[di][7]};
      *(float4*)&dst[(d0 + di) * 64 + e0] = a;
      *(float4*)&dst[(d0 + di) * 64 + e0 + 4] = bq;
    }
  }
  __syncthreads();
  if (w < 2) {
    const float* src = (w == 0) ? ktf : vtf;
#pragma unroll
    for (int di = 0; di < 8; ++di)
#pragma unroll
      for (int ej = 0; ej < 8; ++ej) acc[di][ej] += src[(d0 + di) * 64 + e0 + ej];
  }
  __syncthreads();
  if (w == 1) {
#pragma unroll
    for (int di = 0; di < 8; ++di) {
      float4 a = {acc[di][0], acc[di][1], acc[di][2], acc[di][3]};
      float4 bq = {acc[di][4], acc[di][5], acc[di][6], acc[di][7]};
      *(float4*)&ktf[(d0 + di) * 64 + e0] = a;
      *(float4*)&ktf[(d0 + di) * 64 + e0 + 4] = bq;
    }
  }
  __syncthreads();
  if (w == 0) {
    float* dst = kvp + ((size_t)(c * 64 + bh)) * 4096;
#pragma unroll
    for (int di = 0; di < 8; ++di) {
#pragma unroll
      for (int ej = 0; ej < 8; ++ej) acc[di][ej] += ktf[(d0 + di) * 64 + e0 + ej];
      float4 a = {acc[di][0], acc[di][1], acc[di][2], acc[di][3]};
      float4 bq = {acc[di][4], acc[di][5], acc[di][6], acc[di][7]};
      *(float4*)&dst[(d0 + di) * 64 + e0] = a;
      *(float4*)&dst[(d0 + di) * 64 + e0 + 4] = bq;
    }
  }
  if (t < 64) {
    float tot = ksr[0][t] + ksr[1][t] + ksr[2][t] + ksr[3][t];
    kredp[(size_t)(c * 64 + bh) * 64 + t] = tot;
  }
}

// ---------------- Phase 1.5: reduce chunk partials -> kv, kred
__global__ __launch_bounds__(256) void mh_p15(
    const float* __restrict__ kvp, const float* __restrict__ kredp,
    float* __restrict__ kv, float* __restrict__ kred, int nc) {
  const int i = blockIdx.x * 256 + threadIdx.x;  // 0..262143
  float s = 0.f;
#pragma unroll 1
  for (int c = 0; c < nc; ++c) s += kvp[(size_t)c * (64 * 4096) + i];
  kv[i] = s;
  if (i < 64 * 64) {
    float r = 0.f;
#pragma unroll 1
    for (int c = 0; c < nc; ++c) r += kredp[c * 4096 + i];
    kred[i] = r + 1e-8f;
  }
}

// ---------------- Phase 2: out = z * qh @ KV
// Block = one (b,h) x 128 s-rows. Waves 0,1 -> e in [0,32); waves 2,3 ->
// [32,64) (e-range wave-uniform so kv rows load as s_load; 32-float rows let
// 2-3 rows double-buffer within the SGPR budget). Lane owns one s-row.
// d-loop: 8 chunks x 8 fully unrolled -> ALL register indices static
// (the R2 regression was runtime-indexed qh[] spilling to scratch).
__global__ __launch_bounds__(256, 6) void mh_p2(
    const float* __restrict__ qg, const float* __restrict__ kv,
    const float* __restrict__ kred, float* __restrict__ outg) {
  const int bid = blockIdx.x;        // 0..2047
  const int bh = bid >> 5;           // 0..63
  const int rc = bid & 31;           // 128-row chunk
  const int b = bh >> 4, h = bh & 15;
  const int t = threadIdx.x;
  const int w = t >> 6, lane = t & 63;
  const int eh = w >> 1;                      // e-half, wave-uniform
  const int rr = ((w & 1) << 6) + lane;       // 0..127
  const int s = rc * 128 + rr;
  const int e0 = eh * 32;

  const float* qrow = qg + (size_t)(b * S_ + s) * D_ + h * HD_;
  const float* kvb = kv + (size_t)bh * 4096 + e0;  // uniform -> s_load
  const float* krd = kred + bh * 64;               // uniform

  // first q chunk in flight
  float4 qa = *(const float4*)(qrow);
  float4 qb = *(const float4*)(qrow + 4);

  float acc[32];
#pragma unroll
  for (int e = 0; e < 32; ++e) acc[e] = 0.f;
  float zacc = 0.f;

#pragma unroll 1
  for (int db = 0; db < 8; ++db) {
    float qf[8];
    qf[0] = featmap(qa.x); qf[1] = featmap(qa.y);
    qf[2] = featmap(qa.z); qf[3] = featmap(qa.w);
    qf[4] = featmap(qb.x); qf[5] = featmap(qb.y);
    qf[6] = featmap(qb.z); qf[7] = featmap(qb.w);
    // branchless prefetch of next chunk (wraps to 0 on last iter; L1 hit)
    const int nb = (db + 1) & 7;
    qa = *(const float4*)(qrow + nb * 8);
    qb = *(const float4*)(qrow + nb * 8 + 4);
#pragma unroll
    for (int j = 0; j < 8; ++j) {
      const float qd = qf[j];
      zacc += qd * krd[db * 8 + j];
      const float* row = kvb + (db * 8 + j) * 64;
#pragma unroll
      for (int e = 0; e < 32; ++e) acc[e] += qd * row[e];
    }
  }

  const float z = __builtin_amdgcn_rcpf(zacc);
  float* orow = outg + (size_t)(b * S_ + s) * D_ + h * HD_ + e0;
#pragma unroll
  for (int e4 = 0; e4 < 8; ++e4) {
    float4 o = {acc[e4 * 4] * z, acc[e4 * 4 + 1] * z,
                acc[e4 * 4 + 2] * z, acc[e4 * 4 + 3] * z};
    *(float4*)(orow + e4 * 4) = o;
  }
}

extern "C" void kernel_launch(void* const* d_in, const int* in_sizes, int n_in,
                              void* d_out, int out_size, void* d_ws, size_t ws_size,
                              hipStream_t stream) {
  const float* q = (const float*)d_in[0];
  const float* k = (const float*)d_in[1];
  const float* v = (const float*)d_in[2];
  float* out = (float*)d_out;
  float* ws = (float*)d_ws;

  // choose chunk count by available workspace (nc=16 needs ~17.3 MB)
  const int nc = (ws_size >= (size_t)18 * 1024 * 1024) ? 16 : 8;

  float* kv    = ws;                            // 262144 floats (1 MiB)
  float* kred  = ws + 262144;                   // 4096 floats
  float* kvp   = ws + 262144 + 4096;            // nc * 1 MiB
  float* kredp = kvp + (size_t)nc * 262144;     // nc * 4096 floats

  mh_p1 <<<64 * nc, 256, 0, stream>>>(k, v, kvp, kredp, nc);
  mh_p15<<<1024,    256, 0, stream>>>(kvp, kredp, kv, kred, nc);
  mh_p2 <<<64 * 32, 256, 0, stream>>>(q, kv, kred, out);
}